// Round 11
// baseline (36.670 us; speedup 1.0000x reference)
//
#include <hip/hip_runtime.h>
#include <hip/hip_fp16.h>
#include <stdint.h>

// out[8,8192] = x[8,8192] @ W.T, W[n,k] = nibble(Qidxs[n,k/8], INV[k%8]) - 7.5
// R11: SINGLE dispatch. 512 blocks x 512 threads (8 waves, 2 blocks/CU).
// Block = 16 n-rows; wave owns 1024 K = 32 x mfma_f32_16x16x32_f16.
// B: async global_load_lds (8 x 1KB per wave, XOR-swizzled source + swizzled
//    ds_read_b32, G21) -- max MLP, zero VGPR destinations.
// A: built in-registers from x (L2-resident): 2 float4 loads + 4 cvt_pk + 4 and
//    per step; rows 8..15 masked to zero. No table kernel, no serial prelude.
// End: one barrier + 8-way LDS reduce + coalesced store.

typedef _Float16 half8 __attribute__((ext_vector_type(8)));
typedef float floatx4 __attribute__((ext_vector_type(4)));

union H2U { unsigned u; __half2 h; };
union V4H8 { uint4 u4; half8 h8; };

// nibbles {b, b+4} of w -> f16 pair {n_b, n_{b+4}} - 7.5, exact
__device__ __forceinline__ unsigned unpack_even(unsigned w, __half2 c1, __half2 c2) {
    H2U t; t.u = (w & 0x000F000Fu) | 0x64006400u;      // 1024 + n
    t.h = __hadd2(__hadd2(t.h, c1), c2);               // -1024, -7.5
    return t.u;
}
__device__ __forceinline__ unsigned unpack_odd(unsigned w, __half2 cs, __half2 cc) {
    H2U t; t.u = (w & 0x00F000F0u) | 0x64006400u;      // 1024 + 16n
    t.h = __hfma2(t.h, cs, cc);                        // /16, -71.5
    return t.u;
}

__device__ __forceinline__ void gload_lds16(const void* g, void* l) {
    __builtin_amdgcn_global_load_lds(
        (const __attribute__((address_space(1))) unsigned*)g,
        (__attribute__((address_space(3))) unsigned*)l, 16, 0, 0);
}

#define NWV    8
#define BWAVE  8192                 // 16 rows x 512B, linear (global_load_lds dest)
#define REDOFF (NWV * BWAVE)        // 65536
#define LDS_BYTES (REDOFF + NWV * 128 * 4)   // 69632 -> 2 blocks/CU

__global__ __launch_bounds__(512, 4)
void hi4b_gemm(const float* __restrict__ x, const int* __restrict__ q,
               float* __restrict__ out)
{
    extern __shared__ char lds[];
    const int tid  = threadIdx.x;
    const int lane = tid & 63;
    const int wv   = tid >> 6;            // 0..7: K-window wv*1024 (32 steps)
    const int n0   = blockIdx.x * 16;

    const int r16 = lane & 15;            // n row (B) / C col / A row
    const int u4  = lane >> 4;            // k-group within step

    // ---- stage B async: 16 rows x 512B, source pre-swizzled (G21) ----
    // LDS dest linear: inst j writes [j*1024, j*1024+1024) = rows 2j, 2j+1.
    // LDS chunk (row, c) receives global chunk (row, c ^ (row&7)).
    {
        const int uu = lane >> 5, cc = lane & 31;   // row-half, 16B chunk
        const char* gq = (const char*)q;            // Q row = 4096 B
        char* ldst = lds + wv * BWAVE;
        #pragma unroll
        for (int j = 0; j < 8; ++j) {
            const int row = 2 * j + uu;
            const char* src = gq + (size_t)(n0 + row) * 4096 + wv * 512
                            + ((cc ^ (row & 7)) << 4);
            gload_lds16(src, ldst + j * 1024);
        }
    }
    __builtin_amdgcn_sched_barrier(0);

    // ---- A: straight from x (L2-resident). Step S=wv*32+s: lane needs
    // x[r16][32S + 8*u4 .. +7] (f32), rows >=8 are zeros (mask). ----
    const float4* xr4 = (const float4*)x + (size_t)(r16 & 7) * 2048
                      + wv * 256 + 2 * u4;
    const unsigned rowmask = (r16 < 8) ? 0xFFFFFFFFu : 0u;

    float4 LA[8], LB[8];
    auto loadF = [&](float4 (&L)[8], int t) {      // tile t = steps 4t..4t+3
        #pragma unroll
        for (int i = 0; i < 4; ++i) {
            L[2 * i]     = xr4[32 * t + 8 * i];
            L[2 * i + 1] = xr4[32 * t + 8 * i + 1];
        }
    };
    uint4 F[4];
    auto cvtF = [&](float4 (&L)[8]) {
        #pragma unroll
        for (int i = 0; i < 4; ++i) {
            H2U a0, a1, a2, a3;
            a0.h = __floats2half2_rn(L[2*i].x,   L[2*i].y);
            a1.h = __floats2half2_rn(L[2*i].z,   L[2*i].w);
            a2.h = __floats2half2_rn(L[2*i+1].x, L[2*i+1].y);
            a3.h = __floats2half2_rn(L[2*i+1].z, L[2*i+1].w);
            F[i] = make_uint4(a0.u & rowmask, a1.u & rowmask,
                              a2.u & rowmask, a3.u & rowmask);
        }
    };

    const __half2 c1 = __floats2half2_rn(-1024.0f, -1024.0f);
    const __half2 c2 = __floats2half2_rn(-7.5f, -7.5f);
    const __half2 cs = __floats2half2_rn(0.0625f, 0.0625f);
    const __half2 cc = __floats2half2_rn(-71.5f, -71.5f);

    floatx4 acc = {0.0f, 0.0f, 0.0f, 0.0f};
    // step s: B word (row r16, 4s+u4) at LDS chunk s^(r16&7), word u4
    const char* bp = lds + wv * BWAVE + r16 * 512 + u4 * 4;
    const int sx = (r16 & 7) << 4;

    auto comp4 = [&](int t) {
        #pragma unroll
        for (int i = 0; i < 4; ++i) {
            const int s = 4 * t + i;
            unsigned w  = *(const unsigned*)(bp + ((s << 4) ^ sx));
            unsigned w8 = w >> 8;
            V4H8 Bf;
            Bf.u4.x = unpack_even(w,  c1, c2);   // cols +0,+1 (nib 0,4)
            Bf.u4.y = unpack_odd (w,  cs, cc);   // cols +2,+3 (nib 1,5)
            Bf.u4.z = unpack_even(w8, c1, c2);   // cols +4,+5 (nib 2,6)
            Bf.u4.w = unpack_odd (w8, cs, cc);   // cols +6,+7 (nib 3,7)
            V4H8 A;  A.u4 = F[i];
            acc = __builtin_amdgcn_mfma_f32_16x16x32_f16(A.h8, Bf.h8, acc, 0, 0, 0);
        }
    };

    // ---- pipeline: 8 tiles of 4 steps; x-loads 2 tiles ahead ----
    loadF(LA, 0); loadF(LB, 1);
    cvtF(LA);
    // B staged (gloads are the oldest VMEM ops; wait until only LB outstanding)
    asm volatile("s_waitcnt vmcnt(8)" ::: "memory");
    __builtin_amdgcn_sched_barrier(0);
    comp4(0); loadF(LA, 2);
    cvtF(LB); comp4(1); loadF(LB, 3);
    cvtF(LA); comp4(2); loadF(LA, 4);
    cvtF(LB); comp4(3); loadF(LB, 5);
    cvtF(LA); comp4(4); loadF(LA, 6);
    cvtF(LB); comp4(5); loadF(LB, 7);
    cvtF(LA); comp4(6);
    cvtF(LB); comp4(7);

    // ---- cross-wave reduce: C row = 4*u4 + reg (= b), col = r16 ----
    {
        float* red = (float*)(lds + REDOFF) + wv * 128;
        if (u4 < 2) {
            #pragma unroll
            for (int r = 0; r < 4; ++r)
                red[(u4 * 4 + r) * 16 + r16] = acc[r];
        }
    }
    __syncthreads();
    if (tid < 128) {
        const float* rd = (const float*)(lds + REDOFF);
        float sm = 0.0f;
        #pragma unroll
        for (int wi = 0; wi < NWV; ++wi)
            sm += rd[wi * 128 + tid];
        out[(tid >> 4) * 8192 + n0 + (tid & 15)] = sm;
    }
}

extern "C" void kernel_launch(void* const* d_in, const int* in_sizes, int n_in,
                              void* d_out, int out_size, void* d_ws, size_t ws_size,
                              hipStream_t stream)
{
    const float* x = (const float*)d_in[0];
    const int*   q = (const int*)d_in[1];
    float* out = (float*)d_out;

    hipLaunchKernelGGL(hi4b_gemm, dim3(512), dim3(512), LDS_BYTES, stream,
                       x, q, out);
}

// Round 12
// 16.232 us; speedup vs baseline: 2.2591x; 2.2591x over previous
//
#include <hip/hip_runtime.h>
#include <hip/hip_fp16.h>
#include <stdint.h>

// out[8,8192] = x[8,8192] @ W.T, W[n,k] = nibble(Qidxs[n,k/8], INV[k%8]) - 7.5
// R12 = R5 verbatim (best measured: 16.0 us, single dispatch).
// grid = 256 blocks x 1024 threads (16 waves = 4/SIMD). Block owns 32 n-rows;
// wave w owns K-window w*512 (2 subchunks of 256 K). Wave-private single-buffered
// B+A LDS, register prefetch 1 subchunk ahead, ZERO barriers in main loop
// (same-wave DS ops are in-order -> LDS WAR safe). End: barrier, 16-way LDS
// reduce (aliased over staging LDS), coalesced store.

typedef _Float16 half8 __attribute__((ext_vector_type(8)));
typedef float floatx16 __attribute__((ext_vector_type(16)));

union H2U { unsigned u; __half2 h; };
union V4H8 { uint4 u4; half8 h8; };

// (1024+n) exact -> -1024 -> -7.5  (all exact in f16)
__device__ __forceinline__ unsigned unpack_even(unsigned ws, __half2 c1, __half2 c2) {
    H2U t; t.u = (ws & 0x000F000Fu) | 0x64006400u;
    t.h = __hadd2(__hadd2(t.h, c1), c2);
    return t.u;
}
// (1024+16n) exact -> *1/16 - 71.5 = n - 7.5 (exact fma)
__device__ __forceinline__ unsigned unpack_odd(unsigned ws, __half2 cs, __half2 cc) {
    H2U t; t.u = (ws & 0x00F000F0u) | 0x64006400u;
    t.h = __hfma2(t.h, cs, cc);
    return t.u;
}

#define BPITCH 136                 // 32 words + 8B pad (2-way-free ds_read_b64)
#define BBUF   (32 * BPITCH)       // 4352 B: B buffer (32 rows x 32 words)
#define APITCH 272                 // 16 slots x 16B + zero slot per step
#define ATBL   (16 * APITCH)       // 4352 B: A table (16 K-steps)
#define WLDS   (BBUF + ATBL)       // 8704 B per wave
#define NW     16
#define LDS_BYTES (NW * WLDS)      // 139264 (reduce area aliased at offset 0)

__global__ __launch_bounds__(1024, 4)
void hi4b_gemm(const float* __restrict__ x, const int* __restrict__ q,
               float* __restrict__ out)
{
    extern __shared__ char lds[];
    const int tid  = threadIdx.x;
    const int lane = tid & 63;
    const int wv   = tid >> 6;            // 0..15: K-window wv*512
    const int n0   = blockIdx.x * 32;

    const int nlo = lane & 31;
    const int u   = lane >> 5;
    const int sh  = 8 * u;
    const int c   = lane & 7;             // uint4 within row-subchunk
    const int r0  = lane >> 3;            // 0..7

    const uint4*  q4 = (const uint4*)q;   // 256 uint4 per n-row
    const float4* x4 = (const float4*)x;  // 2048 float4 per b-row

    const int qbase = (n0 + r0) * 256 + wv * 16 + c;     // wv*512k = 16 uint4
    const int slot = lane & 15, shi = lane >> 4;          // steps s = 4i+shi
    const int uu = slot >> 3, rr = slot & 7;
    const int xbase = rr * 2048 + wv * 128 + uu;          // wv*512k = 128 float4

    char* Bw = lds + wv * WLDS;
    char* Aw = Bw + BBUF;

    // zero slot per step (A rows 8..31 are padding) — written once, never overwritten
    if (lane < 16)
        *(uint4*)(Aw + lane * APITCH + 256) = make_uint4(0u, 0u, 0u, 0u);

    uint4 rb0, rb1, rb2, rb3;
    float4 ra[8];

    auto loadB = [&](int sc) {
        int b = qbase + sc * 8;                 // subchunk = 256k = 8 uint4
        rb0 = q4[b];
        rb1 = q4[b +  8 * 256];
        rb2 = q4[b + 16 * 256];
        rb3 = q4[b + 24 * 256];
    };
    auto writeB = [&]() {
        char* p0 = Bw + (r0     ) * BPITCH + c * 16;
        char* p1 = Bw + (r0 +  8) * BPITCH + c * 16;
        char* p2 = Bw + (r0 + 16) * BPITCH + c * 16;
        char* p3 = Bw + (r0 + 24) * BPITCH + c * 16;
        *(uint2*)(p0)     = make_uint2(rb0.x, rb0.y);
        *(uint2*)(p0 + 8) = make_uint2(rb0.z, rb0.w);
        *(uint2*)(p1)     = make_uint2(rb1.x, rb1.y);
        *(uint2*)(p1 + 8) = make_uint2(rb1.z, rb1.w);
        *(uint2*)(p2)     = make_uint2(rb2.x, rb2.y);
        *(uint2*)(p2 + 8) = make_uint2(rb2.z, rb2.w);
        *(uint2*)(p3)     = make_uint2(rb3.x, rb3.y);
        *(uint2*)(p3 + 8) = make_uint2(rb3.z, rb3.w);
    };
    auto loadA = [&](int sc) {
        #pragma unroll
        for (int i = 0; i < 4; ++i) {
            int s = 4 * i + shi;
            int xi = xbase + sc * 64 + 4 * s;   // subchunk = 64 float4
            ra[2 * i]     = x4[xi];
            ra[2 * i + 1] = x4[xi + 2];
        }
    };
    auto writeA = [&]() {
        #pragma unroll
        for (int i = 0; i < 4; ++i) {
            int s = 4 * i + shi;
            H2U a0, a1, a2, a3;
            a0.h = __floats2half2_rn(ra[2*i].x,   ra[2*i].y);
            a1.h = __floats2half2_rn(ra[2*i].z,   ra[2*i].w);
            a2.h = __floats2half2_rn(ra[2*i+1].x, ra[2*i+1].y);
            a3.h = __floats2half2_rn(ra[2*i+1].z, ra[2*i+1].w);
            *(uint4*)(Aw + s * APITCH + slot * 16) = make_uint4(a0.u, a1.u, a2.u, a3.u);
        }
    };

    const __half2 c1 = __floats2half2_rn(-1024.0f, -1024.0f);
    const __half2 c2 = __floats2half2_rn(-7.5f, -7.5f);
    const __half2 cs = __floats2half2_rn(0.0625f, 0.0625f);
    const __half2 cc = __floats2half2_rn(-71.5f, -71.5f);

    floatx16 acc;
    #pragma unroll
    for (int i = 0; i < 16; ++i) acc[i] = 0.0f;

    const int aoff = (nlo < 8) ? (u * 8 + nlo) * 16 : 256;
    const char* ap = Aw + aoff;
    const char* bp = Bw + nlo * BPITCH;

    auto compute = [&]() {
        #pragma unroll
        for (int s = 0; s < 16; ++s) {
            uint2 w2 = *(const uint2*)(bp + s * 8);
            V4H8 A;  A.u4 = *(const uint4*)(ap + s * APITCH);
            unsigned wsa = w2.x >> sh;
            unsigned wsb = w2.y >> sh;
            V4H8 Bf;
            Bf.u4.x = unpack_even(wsa, c1, c2);
            Bf.u4.y = unpack_odd (wsa, cs, cc);
            Bf.u4.z = unpack_even(wsb, c1, c2);
            Bf.u4.w = unpack_odd (wsb, cs, cc);
            acc = __builtin_amdgcn_mfma_f32_32x32x16_f16(A.h8, Bf.h8, acc, 0, 0, 0);
        }
    };

    // ---- pipeline over 2 subchunks, zero barriers ----
    loadB(0); loadA(0);
    writeB(); writeA();        // stage sc0 (waits on loads0)
    loadB(1); loadA(1);        // prefetch sc1 into same regs (issued before compute)
    compute();                 // consume sc0 from LDS
    writeB(); writeA();        // stage sc1 (in-order DS => WAR vs compute reads safe)
    compute();                 // consume sc1

    // ---- cross-wave reduce: 16 tiles of 8 b-rows x 32 n-cols, aliased over staging LDS ----
    __syncthreads();
    {
        float* red = (float*)lds + wv * 256;
        #pragma unroll
        for (int r = 0; r < 4; ++r)
            red[(r + 4 * u) * 32 + nlo] = acc[r];
    }
    __syncthreads();
    if (tid < 256) {
        const int b = tid >> 5, nl = tid & 31;
        const float* rd = (const float*)lds;
        float sm = 0.0f;
        #pragma unroll
        for (int w = 0; w < NW; ++w)
            sm += rd[w * 256 + b * 32 + nl];
        out[b * 8192 + n0 + nl] = sm;
    }
}

extern "C" void kernel_launch(void* const* d_in, const int* in_sizes, int n_in,
                              void* d_out, int out_size, void* d_ws, size_t ws_size,
                              hipStream_t stream)
{
    const float* x = (const float*)d_in[0];
    const int*   q = (const int*)d_in[1];
    float* out = (float*)d_out;

    hipLaunchKernelGGL(hi4b_gemm, dim3(256), dim3(1024), LDS_BYTES, stream,
                       x, q, out);
}